// Round 21
// baseline (302.273 us; speedup 1.0000x reference)
//
#include <hip/hip_runtime.h>
#include <hip/hip_bf16.h>

// NoisyActLin: y = fakequant(x) @ fakequant(W).T + bias
// x: [4,2048,2048] f32 -> M=8192, K=2048 ; W: [8192,2048] f32 -> N=8192
// out: [8192, 8192] f32
//
// R21 = R18 fat-tile core + T4 (counted vmcnt, NEVER 0) on a 4-slot ring.
// History: every round since R9 ended tiles with vmcnt(0) (m218's "drain0"
// anti-pattern, -38..73% vs counted); R5 wrote vmcnt(4) but with "memory"
// clobber (hidden pre-drain, R17 lesson). This round: BK=32, 4 LDS ring
// slots, stage 2 tiles ahead, tile-end = sched_barrier ; plain vmcnt(4) ;
// sched_barrier ; s_barrier. FIFO: in-flight = [kt+1's 4, kt+2's 4] ->
// vmcnt(4) drains exactly kt+1's loads (landing BEFORE barrier, R9 rule).
// WAR: stage targets slot kt-2, readers retired 2 barriers ago.
// ds_read->MFMA left to compiler-counted lgkm (R18's working mechanism).
// Keeps: 64B-row swizzle (0 conflicts), R13 XCD map (FETCH 197MB), fused quant.

using f16x8 = __attribute__((ext_vector_type(8))) _Float16;
using f32x4 = __attribute__((ext_vector_type(4))) float;

#define AS1 __attribute__((address_space(1)))
#define AS3 __attribute__((address_space(3)))

static __device__ __forceinline__ void gload_lds16(const void* g, void* l) {
    __builtin_amdgcn_global_load_lds((const AS1 void*)g, (AS3 void*)l, 16, 0, 0);
}

// ---------------- fused fake-quant: x elementwise + W per-row ----------------
__global__ __launch_bounds__(256) void quant_kernel(
    const float* __restrict__ X,
    const float* __restrict__ las, const float* __restrict__ laq,
    const float* __restrict__ ab,
    const float* __restrict__ W, const float* __restrict__ lws,
    _Float16* __restrict__ Xq, _Float16* __restrict__ Wq) {
    constexpr int K = 2048;
    __shared__ float smn[4], smx[4];
    const int t = threadIdx.x;

    if (blockIdx.x < 8192) {
        const float ls = las[0], lq = laq[0];
        const float s = exp2f(ls);
        const float rs = exp2f(-ls);
        const float q = exp2f(lq);
        const float zp = rintf(ab[0] * rs * 2.0f) * 0.5f * s;  // ACT_GUARD=2
        const float lo = zp;
        const float hi = (zp + q) - s;

        const size_t base = ((size_t)blockIdx.x * 256 + t) * 8;
        float4 v0 = *(const float4*)&X[base];
        float4 v1 = *(const float4*)&X[base + 4];
        float vals[8] = {v0.x, v0.y, v0.z, v0.w, v1.x, v1.y, v1.z, v1.w};

        f16x8 out;
#pragma unroll
        for (int i = 0; i < 8; ++i) {
            float c = fminf(fmaxf(vals[i], lo), hi);
            float qx = rintf((c - zp) * rs);
            out[i] = (_Float16)(qx * s + zp);
        }
        *(f16x8*)&Xq[base] = out;
    } else {
        const int row = blockIdx.x - 8192;
        const float* w = W + (size_t)row * K;

        float4 v0 = ((const float4*)w)[t * 2];
        float4 v1 = ((const float4*)w)[t * 2 + 1];
        float vals[8] = {v0.x, v0.y, v0.z, v0.w, v1.x, v1.y, v1.z, v1.w};

        float mn = vals[0], mx = vals[0];
#pragma unroll
        for (int i = 1; i < 8; ++i) {
            mn = fminf(mn, vals[i]);
            mx = fmaxf(mx, vals[i]);
        }
#pragma unroll
        for (int off = 32; off >= 1; off >>= 1) {
            mn = fminf(mn, __shfl_xor(mn, off));
            mx = fmaxf(mx, __shfl_xor(mx, off));
        }
        if ((t & 63) == 0) { smn[t >> 6] = mn; smx[t >> 6] = mx; }
        __syncthreads();
        mn = fminf(fminf(smn[0], smn[1]), fminf(smn[2], smn[3]));
        mx = fmaxf(fmaxf(smx[0], smx[1]), fmaxf(smx[2], smx[3]));

        const float l = lws[row];
        const float ws = exp2f(l);
        const float rs = exp2f(-l);
        const float qwmin = rintf(mn * rs * 2.0f) * 0.5f * ws;  // WGT_GUARD=2
        const float qwmax = rintf(mx * rs * 2.0f) * 0.5f * ws;

        f16x8 out;
#pragma unroll
        for (int i = 0; i < 8; ++i) {
            float c = fminf(fmaxf(vals[i], qwmin), qwmax);
            float qw = rintf((c - qwmin) * rs);
            out[i] = (_Float16)(qw * ws + qwmin);
        }
        *(f16x8*)&Wq[(size_t)row * K + (size_t)t * 8] = out;
    }
}

// ---------------- GEMM: C[M][N] = A[M][K] * B[N][K]^T + bias ----------------
// LDS 128KB ring: slot s in [0,4): A [256][32] f16 at s*16384 (0..64K),
// B [256][32] at 65536 + s*16384. 8 waves (2Mx4N), 128x64/wave.
// Per K-step kt (slot kt&3, KT=64):
//   STAGET((kt+2)&3, kt+2)   4 gload_lds/thread (32KB tile)
//   12 ds_read_b128 (slot kt&3; compiler-counted lgkm)
//   32 MFMA
//   sched_barrier ; vmcnt(4) [plain: no clobber -> no hidden drain] ;
//   sched_barrier ; s_barrier
// Landing: FIFO in-flight = [kt+1's 4, kt+2's 4]; vmcnt(4) drains kt+1's
//   loads BEFORE the barrier (R9 rule) => after BAR all waves' kt+1 landed.
// WAR: stage targets slot kt+2 mod 4 = kt-2 mod 4; its readers retired via
//   MFMA data-deps before tile kt-2's end barrier (2 barriers ago).
// Tail: clamped re-stages land in dead slots (benign).
__global__ __launch_bounds__(512, 2) void gemm_kernel(
    const _Float16* __restrict__ A, const _Float16* __restrict__ B,
    const float* __restrict__ bias, float* __restrict__ C) {
    constexpr int N = 8192, K = 2048;
    constexpr int KT = K / 32;          // 64 K-steps
    __shared__ char smem[131072];       // A ring: 0..64K, B ring: 64K..128K

    // L2/L3-aware mapping (R13): XCD x owns A-band [4x,4x+4); bm fastest.
    const int bid = blockIdx.x;
    const int j = bid >> 3;
    const int bm = (bid & 7) * 4 + (j & 3);
    const int bn = j >> 2;

    const int t = threadIdx.x;
    const int lane = t & 63;
    const int wid = t >> 6;
    const int wr = wid >> 2;            // 0..1 (M half)
    const int wc = wid & 3;             // 0..3 (N quarter)
    const int l15 = lane & 15;
    const int lq = lane >> 4;

    // staging: tile [256 rows][32 k] f16 = 16KB per matrix, 64B rows, linear
    // LDS dest, pre-swizzled global source (byte bit5 ^= bit9 = row bit3).
    // R2/R3/R9-verified: 0 bank conflicts. Thread t covers bytes d0 (rows
    // 0-127) and d1 = d0+8192 (rows 128-255).
    const int d0 = t * 16, d1 = d0 + 8192;
    const int r0 = d0 >> 6, c0e = (((d0 & 63) ^ (((d0 >> 9) & 1) << 5)) >> 1);
    const int r1 = d1 >> 6, c1e = (((d1 & 63) ^ (((d1 >> 9) & 1) << 5)) >> 1);
    const _Float16* Agb = A + (size_t)bm * 256 * K;
    const _Float16* Bgb = B + (size_t)bn * 256 * K;

    // read-side swizzled k-col byte offset (bit9 of addr = row bit3 = l15 bit3)
    const int cp = (lq * 16) ^ ((l15 & 8) << 2);

    f32x4 acc[8][4] = {};
    f16x8 fA[8], fB[4];

#define STAGET(SLOT, KS) do {                                                  \
        const _Float16* _ga = Agb + (size_t)(KS) * 32;                         \
        char* _la = smem + (SLOT) * 16384;                                     \
        gload_lds16(_ga + (size_t)r0 * K + c0e, _la + d0);                     \
        gload_lds16(_ga + (size_t)r1 * K + c1e, _la + d1);                     \
        const _Float16* _gb = Bgb + (size_t)(KS) * 32;                         \
        char* _lb = smem + 65536 + (SLOT) * 16384;                             \
        gload_lds16(_gb + (size_t)r0 * K + c0e, _lb + d0);                     \
        gload_lds16(_gb + (size_t)r1 * K + c1e, _lb + d1);                     \
    } while (0)

#define SB() __builtin_amdgcn_sched_barrier(0)

    // ---- prologue: stage tiles 0,1; counted wait for tile 0; barrier ----
    STAGET(0, 0);
    STAGET(1, 1);
    SB();
    asm volatile("s_waitcnt vmcnt(4)");   // tile 0's 4 loads landed
    SB();
    __builtin_amdgcn_s_barrier();

    for (int kt = 0; kt < KT; ++kt) {
        const int slot = kt & 3;
        const int nslot = (kt + 2) & 3;
        const int nx = (kt + 2 < KT) ? kt + 2 : KT - 1;

        STAGET(nslot, nx);               // 4 loads for tile kt+2

        // 12 ds_read_b128 of tile kt (compiler inserts counted lgkm)
        const char* _a = smem + slot * 16384 + (wr * 128 + l15) * 64 + cp;
        const char* _b = smem + 65536 + slot * 16384 +
                         (wc * 64 + l15) * 64 + cp;
#pragma unroll
        for (int m = 0; m < 8; ++m)
            fA[m] = *(const f16x8*)(_a + m * 1024);
#pragma unroll
        for (int n = 0; n < 4; ++n)
            fB[n] = *(const f16x8*)(_b + n * 1024);

        // 32 MFMA — pure data deps
#pragma unroll
        for (int m = 0; m < 8; ++m)
#pragma unroll
            for (int n = 0; n < 4; ++n)
                acc[m][n] = __builtin_amdgcn_mfma_f32_16x16x32_f16(
                    fA[m], fB[n], acc[m][n], 0, 0, 0);

        // T4: counted vmcnt, never 0. In-flight = [kt+1's 4, kt+2's 4];
        // vmcnt(4) drains kt+1's loads. sched_barrier pins order without a
        // memory clobber (no hidden compiler drain — R17 lesson).
        SB();
        asm volatile("s_waitcnt vmcnt(4)");
        SB();
        __builtin_amdgcn_s_barrier();    // => all waves' kt+1 stages landed
    }
#undef STAGET
#undef SB

    // ---- epilogue: C/D mapping col=lane&15, row=(lane>>4)*4+reg ----
#pragma unroll
    for (int m = 0; m < 8; ++m) {
        const int row = bm * 256 + wr * 128 + m * 16 + lq * 4;
#pragma unroll
        for (int n = 0; n < 4; ++n) {
            const int col = bn * 256 + wc * 64 + n * 16 + l15;
            const float bv = bias[col];
#pragma unroll
            for (int r = 0; r < 4; ++r) {
                C[(size_t)(row + r) * N + col] = acc[m][n][r] + bv;
            }
        }
    }
}

extern "C" void kernel_launch(void* const* d_in, const int* in_sizes, int n_in,
                              void* d_out, int out_size, void* d_ws, size_t ws_size,
                              hipStream_t stream) {
    const float* x    = (const float*)d_in[0];   // [4,2048,2048]
    const float* w    = (const float*)d_in[1];   // [8192,2048]
    const float* bias = (const float*)d_in[2];   // [8192]
    const float* las  = (const float*)d_in[3];   // log_act_s [1]
    const float* laq  = (const float*)d_in[4];   // log_act_q [1]
    const float* ab   = (const float*)d_in[5];   // act_b [1]
    const float* lws  = (const float*)d_in[6];   // log_wght_s [8192]
    float* out = (float*)d_out;

    constexpr size_t MK = (size_t)8192 * 2048;
    _Float16* xq = (_Float16*)d_ws;
    _Float16* wq = (_Float16*)((char*)d_ws + MK * sizeof(_Float16));

    quant_kernel<<<16384, 256, 0, stream>>>(x, las, laq, ab, w, lws, xq, wq);
    gemm_kernel<<<1024, 512, 0, stream>>>(xq, wq, bias, out);
}